// Round 1
// baseline (366.719 us; speedup 1.0000x reference)
//
#include <hip/hip_runtime.h>
#include <hip/hip_bf16.h>
#include <math.h>

// Problem: x [N=2048, C=512, H=7, W=7] fp32.
// y[n,c] = mean_{hw} x; per-n: m = mean_c y, var = mean_c y^2 - m^2 (clamped >=0)
// gate = exp(-0.5*C_PARAM*((y-m)*rsqrt(var+eps))^2), C_PARAM=2 -> exp(-yn^2)
// out = x * gate (broadcast over spatial)

#define NN 2048
#define CC 512
#define HW 49
#define EPS 1e-5f

__global__ __launch_bounds__(512) void gate_kernel(const float* __restrict__ x,
                                                   float* __restrict__ out) {
    const int n = blockIdx.x;
    const int c = threadIdx.x;   // 512 threads, one per channel

    const size_t base = ((size_t)n * CC + c) * HW;
    const float* xp = x + base;

    // Load this channel's 49 spatial elements into registers; accumulate sum.
    float v[HW];
    float s = 0.0f;
#pragma unroll
    for (int i = 0; i < HW; ++i) {
        v[i] = xp[i];
        s += v[i];
    }
    const float y = s * (1.0f / (float)HW);   // spatial mean for (n,c)

    // Block-wide reduction over 512 channels: sum(y) and sum(y*y).
    float sum = y;
    float sum2 = y * y;
#pragma unroll
    for (int off = 32; off > 0; off >>= 1) {
        sum  += __shfl_down(sum, off);
        sum2 += __shfl_down(sum2, off);
    }

    __shared__ float wsum[8];
    __shared__ float wsum2[8];
    const int wave = threadIdx.x >> 6;
    const int lane = threadIdx.x & 63;
    if (lane == 0) {
        wsum[wave] = sum;
        wsum2[wave] = sum2;
    }
    __syncthreads();

    __shared__ float s_m, s_inv;
    if (threadIdx.x == 0) {
        float ts = 0.0f, ts2 = 0.0f;
#pragma unroll
        for (int w = 0; w < 8; ++w) {
            ts += wsum[w];
            ts2 += wsum2[w];
        }
        const float m = ts * (1.0f / (float)CC);
        float var = ts2 * (1.0f / (float)CC) - m * m;
        var = fmaxf(var, 0.0f);
        s_m = m;
        s_inv = rsqrtf(var + EPS);
    }
    __syncthreads();

    const float yn = (y - s_m) * s_inv;
    const float gate = expf(-yn * yn);   // C_PARAM=2: exp(-0.5*2*yn^2)

    float* op = out + base;
#pragma unroll
    for (int i = 0; i < HW; ++i) {
        op[i] = v[i] * gate;
    }
}

extern "C" void kernel_launch(void* const* d_in, const int* in_sizes, int n_in,
                              void* d_out, int out_size, void* d_ws, size_t ws_size,
                              hipStream_t stream) {
    const float* x = (const float*)d_in[0];
    float* out = (float*)d_out;
    gate_kernel<<<NN, CC, 0, stream>>>(x, out);
}

// Round 2
// 346.012 us; speedup vs baseline: 1.0598x; 1.0598x over previous
//
#include <hip/hip_runtime.h>
#include <math.h>

// x [N=2048, C=512, H*W=49] fp32.
// y[n,c] = spatial mean; per-n channel mean/var -> inv_std; gate = exp(-yn^2)
// out = x * gate.
//
// Strategy: fully coalesced float4 global access via LDS transpose chunks.
// Thread t owns channel t (x values register-resident, v[49]).
// 4 chunks of 128 channels (6272 floats = 24.5 KB LDS) per sample.

#define NN 2048
#define CC 512
#define HW 49
#define CHCH 128            // channels per chunk (2 waves' worth)
#define CHEL (CHCH * HW)    // 6272 floats per chunk
#define CHV4 (CHEL / 4)     // 1568 float4 per chunk
#define NCHUNK (CC / CHCH)  // 4
#define EPS 1e-5f

__global__ __launch_bounds__(512, 4) void gate_kernel(const float* __restrict__ x,
                                                      float* __restrict__ out) {
    __shared__ float lds[CHEL];
    __shared__ float wsum[8];
    __shared__ float wsum2[8];
    __shared__ float s_m, s_inv;

    const int n = blockIdx.x;
    const int tid = threadIdx.x;           // == channel owned by this thread
    const size_t nbase = (size_t)n * (CC * HW);

    float v[HW];

    // ---- Phase 1: coalesced stage + per-channel extraction ----
    const float4* __restrict__ xin4 = (const float4*)(x + nbase);
    for (int j = 0; j < NCHUNK; ++j) {
        for (int i = tid; i < CHV4; i += 512) {
            ((float4*)lds)[i] = xin4[j * CHV4 + i];
        }
        __syncthreads();
        if ((tid >> 7) == j) {             // wave-uniform: 2 waves own this chunk
            const int base = (tid & (CHCH - 1)) * HW;
#pragma unroll
            for (int l = 0; l < HW; ++l) v[l] = lds[base + l];
        }
        __syncthreads();
    }

    // ---- Phase 2: stats ----
    float s = 0.0f;
#pragma unroll
    for (int l = 0; l < HW; ++l) s += v[l];
    const float y = s * (1.0f / (float)HW);

    float sum = y, sum2 = y * y;
#pragma unroll
    for (int off = 32; off > 0; off >>= 1) {
        sum  += __shfl_down(sum, off);
        sum2 += __shfl_down(sum2, off);
    }
    const int wave = tid >> 6;
    const int lane = tid & 63;
    if (lane == 0) { wsum[wave] = sum; wsum2[wave] = sum2; }
    __syncthreads();
    if (tid == 0) {
        float ts = 0.0f, ts2 = 0.0f;
#pragma unroll
        for (int w = 0; w < 8; ++w) { ts += wsum[w]; ts2 += wsum2[w]; }
        const float m = ts * (1.0f / (float)CC);
        float var = ts2 * (1.0f / (float)CC) - m * m;
        var = fmaxf(var, 0.0f);
        s_m = m;
        s_inv = rsqrtf(var + EPS);
    }
    __syncthreads();

    const float yn = (y - s_m) * s_inv;
    const float gate = expf(-yn * yn);     // C_PARAM=2 -> exp(-0.5*2*yn^2)

    // ---- Phase 3: registers*gate -> LDS -> coalesced float4 store ----
    float4* __restrict__ out4 = (float4*)(out + nbase);
    for (int j = 0; j < NCHUNK; ++j) {
        if ((tid >> 7) == j) {
            const int base = (tid & (CHCH - 1)) * HW;
#pragma unroll
            for (int l = 0; l < HW; ++l) lds[base + l] = v[l] * gate;
        }
        __syncthreads();
        for (int i = tid; i < CHV4; i += 512) {
            out4[j * CHV4 + i] = ((float4*)lds)[i];
        }
        __syncthreads();
    }
}

extern "C" void kernel_launch(void* const* d_in, const int* in_sizes, int n_in,
                              void* d_out, int out_size, void* d_ws, size_t ws_size,
                              hipStream_t stream) {
    const float* x = (const float*)d_in[0];
    float* out = (float*)d_out;
    gate_kernel<<<NN, 512, 0, stream>>>(x, out);
}